// Round 13
// baseline (30.593 us; speedup 1.0000x reference)
//
#include <hip/hip_runtime.h>

// PixelEffectModule: 8-bin intensity histogram over 11x11 windows at stride 8,
// argmax bin, output that bin's mean RGB, upsampled 8x8.
// Input: rgb (1,3,2048,2048) fp32 in [0,255). Output: (1,3,2048,2048) fp32.
//
// R13 = R12's green DMA-staged structure (absmax 0.0, 25.9 us) + cross-tile
// pipelining (T3/T4 counted-vmcnt pattern):
//  - each WG handles TWO horizontally-adjacent tiles (slots 2s, 2s+1) with
//    double-buffered LDS (2 x 36.9 KB).
//  - issue A's 9 + B's 9 global_load_lds up front; s_waitcnt vmcnt(9) -> A
//    ready, B STAYS IN FLIGHT; barrier; compute A (overlaps B's DMA);
//    store A; s_waitcnt vmcnt(6) -> B loads done (A's 6 stores may remain);
//    barrier; compute B.
//  - internal reduce barriers are raw s_barrier + lgkmcnt(0)-only waits
//    (m201 pattern, rule-18 sched_barrier fences) so they don't drain vmcnt.
//  - compute path byte-identical to R12 (counts, nibbles, argmax, reduces,
//    row writes, swizzle swz(w)=w^(((w>>3)&3)<<1) both-sides).
// Tripwires: absmax != 0 -> raw-barrier race; WRITE > 60 MB -> spill;
// dur >= 26 us -> occupancy loss (2 WG/CU) beat the overlap gain.

#define Wd 2048
#define HW (2048 * 2048)
#define BUF_F 9216   // floats per LDS buffer (2304 chunks x 4)

typedef unsigned int u32;
typedef unsigned long long u64;
typedef float f32x4 __attribute__((ext_vector_type(4)));

// correctly-rounded t/3 (Markstein), 3 ops vs ~9-inst div expansion
__device__ __forceinline__ float div3(float t) {
    const float c = 0x1.555556p-2f;  // RN(1/3)
    float q0 = t * c;
    float r  = __builtin_fmaf(q0, -3.0f, t);
    return __builtin_fmaf(r, c, q0);
}

// 16B-chunk bank swizzle within a 66-chunk row (involution; 64,65 fixed pts)
__device__ __forceinline__ u32 swz(u32 w) { return w ^ (((w >> 3) & 3u) << 1); }

// lgkmcnt-only workgroup sync: does NOT drain vmcnt (keeps B's DMA in flight)
__device__ __forceinline__ void wgsync_lgkm() {
    asm volatile("s_waitcnt lgkmcnt(0)" ::: "memory");
    __builtin_amdgcn_sched_barrier(0);
    __builtin_amdgcn_s_barrier();
    __builtin_amdgcn_sched_barrier(0);
}

// issue 9 global_load_lds per thread for one 32-cell tile (linear LDS dest,
// inverse-swizzled global source; OOB lanes clamped into the pad region)
__device__ __forceinline__ void stage_tile(const float* __restrict__ rgb,
                                           float* ldsbase, int tid, int lane,
                                           u32 slot) {
    const int oyS    = (int)(slot >> 3);
    const int bxS    = (int)(slot & 7u);
    const int xstart = bxS ? (bxS * 256 - 8) : 0;
    const int ytopS  = oyS * 8 - 5;
#pragma unroll
    for (int it = 0; it < 9; ++it) {
        u32 cbase = (u32)it * 256u + (u32)(tid & ~63);  // wave-uniform
        u32 c = cbase + (u32)lane;
        c = c < 2177u ? c : 2177u;                      // clamp -> junk to pad
        u32 ch  = c / 726u;
        u32 rem = c - ch * 726u;
        u32 row = rem / 66u;
        u32 wph = rem - row * 66u;                      // physical chunk-in-row
        u32 wlog = swz(wph);                            // logical chunk to fetch
        int y = ytopS + (int)row; y = y < 0 ? 0 : y;    // clamped rows unread
        const float* gsrc = rgb + (size_t)ch * HW + (size_t)y * Wd
                          + (size_t)(xstart + (int)(wlog * 4u));
        float* ldst = ldsbase + cbase * 4u;             // wave-uniform base
        __builtin_amdgcn_global_load_lds(
            (const __attribute__((address_space(1))) void*)gsrc,
            (__attribute__((address_space(3))) void*)ldst, 16, 0, 0);
    }
}

// full per-tile compute: R12's verified math path, raw-barrier syncs
__device__ __forceinline__ void compute_tile(const float* __restrict__ lbase,
                                             float* __restrict__ out,
                                             u64 (*sc)[32], float4 (*ss)[32],
                                             int tid, u32 slot) {
    const int w    = tid >> 6;                 // wave 0..3
    const int half = (tid >> 5) & 1;           // half-wave
    const int cl   = tid & 31;                 // cell within 32-strip
    const int p    = 2 * w + half;             // row-band part 0..7

    const int oy  = (int)(slot >> 3);
    const int bx8 = (int)(slot & 7u);
    const int ox  = bx8 * 32 + cl;
    const int xstart = bx8 ? (bx8 * 256 - 8) : 0;
    const int ytop   = oy * 8 - 5;

    const int lx_off = (ox == 0) ? 0 : (8 * ox - 8 - xstart);  // mult of 8
    const int w0     = lx_off >> 2;                            // even chunk idx
    const u32 vmask  = (ox == 0) ? 0x003Fu : 0x3FF8u;
    const int rs = (p < 3) ? 2 * p : (3 + p);  // first window-row of this part
    const int nr = (p < 3) ? 2 : 1;            // rows: 2,2,2,1,1,1,1,1

#define LOADROW(dst, chn, rr)                                                   \
    {                                                                           \
        int rb_ = ((chn) * 11 + (rr)) * 66;                                     \
        *(f32x4*)((dst) + 0)  = *(const f32x4*)&lbase[(u32)(rb_ + swz(w0+0))*4u];\
        *(f32x4*)((dst) + 4)  = *(const f32x4*)&lbase[(u32)(rb_ + swz(w0+1))*4u];\
        *(f32x4*)((dst) + 8)  = *(const f32x4*)&lbase[(u32)(rb_ + swz(w0+2))*4u];\
        *(f32x4*)((dst) + 12) = *(const f32x4*)&lbase[(u32)(rb_ + swz(w0+3))*4u];\
    }

    // ---- pass 1: bin pixels, packed byte counts + nibble cache ----
    u64 c64 = 0;
    u32 nbl[2], nbh[2];
#pragma unroll
    for (int k = 0; k < 2; ++k) {
        nbl[k] = 0xFFFFFFFFu; nbh[k] = 0xFFFFFFFFu;
        int r = rs + k;
        int y = ytop + r;                      // uniform per half-wave
        if (k < nr && y >= 0) {
            float vR[16], vG[16], vB[16];
            LOADROW(vR, 0, r) LOADROW(vG, 1, r) LOADROW(vB, 2, r)
            u32 bl = 0, bh = 0;
#pragma unroll
            for (int j = 0; j < 14; ++j) {
                float m = div3(vR[j] + vG[j] + vB[j]);
                u32 bin = (u32)(m * 0.03125f);     // trunc(mean/32), exact
                u32 valid = (vmask >> j) & 1u;
                c64 += (u64)valid << (bin << 3);
                u32 binv = valid ? bin : 15u;      // 15 matches no bin
                if (j < 8) bl |= binv << (4 * j);
                else       bh |= binv << (4 * (j - 8));
            }
            nbl[k] = bl; nbh[k] = bh;
        }
    }

    // ---- cross-half reduce (parts 2w, 2w+1), then 4-wave LDS reduce ----
    c64 += __shfl_xor(c64, 32);
    if (half == 0) sc[w][cl] = c64;
    wgsync_lgkm();

    u64 tot = sc[0][cl] + sc[1][cl] + sc[2][cl] + sc[3][cl];   // bytes <=121
    u32 lo = (u32)tot, hi = (u32)(tot >> 32);
    u32 best = 0, bc = lo & 0xFFu;
#pragma unroll
    for (int b = 1; b < 8; ++b) {
        u32 cb = ((b < 4 ? lo : hi) >> ((b & 3) * 8)) & 0xFFu;
        bool t = cb > bc;
        bc   = t ? cb : bc;
        best = t ? (u32)b : best;
    }

    // ---- pass 2: re-read LDS (cheap), sum winning bin via nibbles ----
    float sr = 0.f, sg = 0.f, sb = 0.f;
#pragma unroll
    for (int k = 0; k < 2; ++k) {
        int r = rs + k;
        int y = ytop + r;
        if (k < nr && y >= 0) {
            float vR[16], vG[16], vB[16];
            LOADROW(vR, 0, r) LOADROW(vG, 1, r) LOADROW(vB, 2, r)
            u32 bl = nbl[k], bh = nbh[k];
#pragma unroll
            for (int j = 0; j < 14; ++j) {
                u32 bin = ((j < 8) ? (bl >> (4 * j))
                                   : (bh >> (4 * (j - 8)))) & 0xFu;
                float hm = (bin == best) ? 1.0f : 0.0f;
                sr = __builtin_fmaf(hm, vR[j], sr);
                sg = __builtin_fmaf(hm, vG[j], sg);
                sb = __builtin_fmaf(hm, vB[j], sb);
            }
        }
    }
    sr += __shfl_xor(sr, 32);
    sg += __shfl_xor(sg, 32);
    sb += __shfl_xor(sb, 32);

    if (half == 0) ss[w][cl] = make_float4(sr, sg, sb, 0.f);
    wgsync_lgkm();

    float4 s0 = ss[0][cl], s1 = ss[1][cl], s2 = ss[2][cl], s3 = ss[3][cl];
    float fbc = (float)bc;
    float orv = (s0.x + s1.x + s2.x + s3.x) / fbc;
    float ogv = (s0.y + s1.y + s2.y + s3.y) / fbc;
    float obv = (s0.z + s1.z + s2.z + s3.z) / fbc;

    // ---- write: part p owns row p of the 8x8 block, 2x float4 per channel ----
    size_t base = (size_t)(oy * 8 + p) * Wd + (size_t)(ox * 8);
    float vals[3] = { orv, ogv, obv };
#pragma unroll
    for (int c = 0; c < 3; ++c) {
        float v = vals[c];
        float4 vv = make_float4(v, v, v, v);
        float* o = out + (size_t)c * HW + base;
        ((float4*)o)[0] = vv;
        ((float4*)o)[1] = vv;
    }
#undef LOADROW
}

__global__ __launch_bounds__(256, 2)
void pixel_effect_kernel(const float* __restrict__ rgb, float* __restrict__ out) {
    __shared__ float  ldsf[2 * BUF_F];   // double buffer, 73.7 KB
    __shared__ u64    sc[4][32];
    __shared__ float4 ss[4][32];

    const int tid  = threadIdx.x;
    const int lane = tid & 63;

    // XCD swizzle over PAIRS (grid 1024 = 8*128, bijective): XCD (wgid&7)
    // owns pair-slots [128*xcd, 128*xcd+128) = 32 contiguous cell-rows.
    u32 wgid = blockIdx.x;
    u32 s    = (wgid & 7u) * 128u + (wgid >> 3);
    u32 slotA = 2u * s;
    u32 slotB = 2u * s + 1u;

    // issue both tiles' DMA (18 insts/thread in flight)
    stage_tile(rgb, ldsf,         tid, lane, slotA);
    stage_tile(rgb, ldsf + BUF_F, tid, lane, slotB);

    // wait tile A only (9 B-loads stay outstanding), sync, compute A
    asm volatile("s_waitcnt vmcnt(9)" ::: "memory");
    __builtin_amdgcn_sched_barrier(0);
    __builtin_amdgcn_s_barrier();
    __builtin_amdgcn_sched_barrier(0);
    compute_tile(ldsf, out, sc, ss, tid, slotA);

    // A's 6 stores may remain outstanding; B's loads must be done
    asm volatile("s_waitcnt vmcnt(6)" ::: "memory");
    __builtin_amdgcn_sched_barrier(0);
    __builtin_amdgcn_s_barrier();
    __builtin_amdgcn_sched_barrier(0);
    compute_tile(ldsf + BUF_F, out, sc, ss, tid, slotB);
}

extern "C" void kernel_launch(void* const* d_in, const int* in_sizes, int n_in,
                              void* d_out, int out_size, void* d_ws, size_t ws_size,
                              hipStream_t stream) {
    const float* rgb = (const float*)d_in[0];
    float* out = (float*)d_out;
    dim3 block(256, 1, 1);                // 4 waves; wave = 32 cells x 2 parts
    dim3 grid(1024, 1, 1);                // 1024 WGs x 2 tiles = 2048 tiles
    hipLaunchKernelGGL(pixel_effect_kernel, grid, block, 0, stream, rgb, out);
}

// Round 14
// 25.243 us; speedup vs baseline: 1.2119x; 1.2119x over previous
//
#include <hip/hip_runtime.h>

// PixelEffectModule: 8-bin intensity histogram over 11x11 windows at stride 8,
// argmax bin, output that bin's mean RGB, upsampled 8x8.
// Input: rgb (1,3,2048,2048) fp32 in [0,255). Output: (1,3,2048,2048) fp32.
//
// R14 = R12's green schedule (DMA stage -> __syncthreads -> compute; overlap
// from co-resident WGs) with finer pipelines + optimal bank swizzle:
//  - 16-cell tiles, 128-thread WGs (2 waves; wave = 16 cells x 4 parts in
//    16-lane quarters). LDS 18.9 KB -> 8 WG/CU (R12: 4) = twice the
//    independent stage<->compute streams per CU. R13 lesson: overlap comes
//    from WG count, not intra-WG vmcnt choreography (2 WG/CU regressed).
//  - swz2(w) = w ^ ((w>>3)&3): involution on 16B chunks within a 34-chunk
//    row (32,33 fixed). Consecutive 8 lanes hit all 8 bank groups ->
//    ds_read_b128 at the 128B/cyc floor (R13 measured 1.18M conflicts with
//    the old swz; predicted ~0 now). Linear LDS dest + inverse-swizzled
//    global source + swizzled reads (both-sides rule).
//  - reduces: shfl_xor(16)+shfl_xor(32) within wave (4 parts), then 2-wave
//    LDS reduce. Math path (bins, packed-u64 counts, nibble cache, argmax,
//    row writes) byte-identical to R12.

#define Wd 2048
#define HW (2048 * 2048)
#define CPR 34      // 16B chunks per staged row (136 floats)
#define CPC 374     // chunks per channel (11 * 34)
#define NCHK 1122   // total chunks (3 * 374)
#define PADC 1152   // padded chunk count (9 iters * 128 threads)

typedef unsigned int u32;
typedef unsigned long long u64;
typedef float f32x4 __attribute__((ext_vector_type(4)));

// correctly-rounded t/3 (Markstein), 3 ops vs ~9-inst div expansion
__device__ __forceinline__ float div3(float t) {
    const float c = 0x1.555556p-2f;  // RN(1/3)
    float q0 = t * c;
    float r  = __builtin_fmaf(q0, -3.0f, t);
    return __builtin_fmaf(r, c, q0);
}

// chunk bank swizzle: involution for w<34 (32,33 fixed points); spreads
// stride-2-chunk lane patterns across all 8 bank groups
__device__ __forceinline__ u32 swz2(u32 w) { return w ^ ((w >> 3) & 3u); }

__global__ __launch_bounds__(128, 4)
void pixel_effect_kernel(const float* __restrict__ rgb, float* __restrict__ out) {
    __shared__ float  ldsf[PADC * 4];   // 18.4 KB staged tile
    __shared__ u64    sc[2][16];
    __shared__ float4 ss[2][16];

    const int tid  = threadIdx.x;       // 0..127
    const int lane = tid & 63;
    const int w    = tid >> 6;          // wave 0..1
    const int qid  = (tid >> 4) & 3;    // quarter within wave
    const int cl   = tid & 15;          // cell within 16-strip
    const int p    = w * 4 + qid;       // row-band part 0..7

    // XCD swizzle (grid 4096 = 8*512, bijective): XCD (wgid&7) owns slots
    // [512*xcd, 512*xcd+512) = 32 contiguous cell-rows.
    u32 wgid = blockIdx.x;
    u32 slot = (wgid & 7u) * 512u + (wgid >> 3);
    const int oy = (int)(slot >> 4);
    const int tx = (int)(slot & 15u);
    const int ox = tx * 16 + cl;

    const int xstart = tx ? (tx * 128 - 8) : 0;   // staged 136-float span
    const int ytop   = oy * 8 - 5;

    // ---- DMA stage: 1122 chunks global -> LDS (linear dest, pre-swz src) ----
#pragma unroll
    for (int it = 0; it < 9; ++it) {
        u32 cbase = (u32)it * 128u + (u32)(tid & ~63);  // wave-uniform
        u32 c = cbase + (u32)lane;
        c = c < (NCHK - 1) ? c : (NCHK - 1);            // clamp -> junk to pad
        u32 ch  = c / CPC;
        u32 rem = c - ch * CPC;
        u32 row = rem / CPR;
        u32 wph = rem - row * CPR;                      // physical chunk-in-row
        u32 wlog = swz2(wph);                           // logical chunk to fetch
        int y = ytop + (int)row; y = y < 0 ? 0 : y;     // clamped rows unread
        const float* gsrc = rgb + (size_t)ch * HW + (size_t)y * Wd
                          + (size_t)(xstart + (int)(wlog * 4u));
        float* ldst = &ldsf[cbase * 4u];                // wave-uniform base
        __builtin_amdgcn_global_load_lds(
            (const __attribute__((address_space(1))) void*)gsrc,
            (__attribute__((address_space(3))) void*)ldst, 16, 0, 0);
    }
    __syncthreads();   // drains vmcnt before barrier (R12 green schedule)

    // slot j maps row-local x = lx_off + j. Interior: j in [3,13]; ox==0:
    // j in [0,5]. 16-float read [lx_off, lx_off+16) always within the row.
    const int lx_off = (ox == 0) ? 0 : (8 * ox - 8 - xstart);  // mult of 8
    const int w0     = lx_off >> 2;                            // even chunk idx
    const u32 vmask  = (ox == 0) ? 0x003Fu : 0x3FF8u;
    const int rs = (p < 3) ? 2 * p : (3 + p);  // first window-row of this part
    const int nr = (p < 3) ? 2 : 1;            // rows: 2,2,2,1,1,1,1,1

#define LOADROW(dst, chn, rr)                                                    \
    {                                                                            \
        int rb_ = ((chn) * 11 + (rr)) * CPR;                                     \
        *(f32x4*)((dst) + 0)  = *(const f32x4*)&ldsf[(u32)(rb_ + swz2(w0+0))*4u];\
        *(f32x4*)((dst) + 4)  = *(const f32x4*)&ldsf[(u32)(rb_ + swz2(w0+1))*4u];\
        *(f32x4*)((dst) + 8)  = *(const f32x4*)&ldsf[(u32)(rb_ + swz2(w0+2))*4u];\
        *(f32x4*)((dst) + 12) = *(const f32x4*)&ldsf[(u32)(rb_ + swz2(w0+3))*4u];\
    }

    // ---- pass 1: bin pixels, packed byte counts + nibble cache ----
    u64 c64 = 0;
    u32 nbl[2], nbh[2];
#pragma unroll
    for (int k = 0; k < 2; ++k) {
        nbl[k] = 0xFFFFFFFFu; nbh[k] = 0xFFFFFFFFu;
        int r = rs + k;
        int y = ytop + r;                      // uniform per quarter
        if (k < nr && y >= 0) {
            float vR[16], vG[16], vB[16];
            LOADROW(vR, 0, r) LOADROW(vG, 1, r) LOADROW(vB, 2, r)
            u32 bl = 0, bh = 0;
#pragma unroll
            for (int j = 0; j < 14; ++j) {
                float m = div3(vR[j] + vG[j] + vB[j]);
                u32 bin = (u32)(m * 0.03125f);     // trunc(mean/32), exact
                u32 valid = (vmask >> j) & 1u;
                c64 += (u64)valid << (bin << 3);
                u32 binv = valid ? bin : 15u;      // 15 matches no bin
                if (j < 8) bl |= binv << (4 * j);
                else       bh |= binv << (4 * (j - 8));
            }
            nbl[k] = bl; nbh[k] = bh;
        }
    }

    // ---- reduce counts: 4 parts within wave (xor16, xor32), then 2 waves ----
    c64 += __shfl_xor(c64, 16);
    c64 += __shfl_xor(c64, 32);
    if (qid == 0) sc[w][cl] = c64;
    __syncthreads();

    u64 tot = sc[0][cl] + sc[1][cl];           // bytes <= 121: no carries
    u32 lo = (u32)tot, hi = (u32)(tot >> 32);
    u32 best = 0, bc = lo & 0xFFu;
#pragma unroll
    for (int b = 1; b < 8; ++b) {
        u32 cb = ((b < 4 ? lo : hi) >> ((b & 3) * 8)) & 0xFFu;
        bool t = cb > bc;
        bc   = t ? cb : bc;
        best = t ? (u32)b : best;
    }

    // ---- pass 2: re-read LDS (cheap), sum winning bin via nibbles ----
    float sr = 0.f, sg = 0.f, sb = 0.f;
#pragma unroll
    for (int k = 0; k < 2; ++k) {
        int r = rs + k;
        int y = ytop + r;
        if (k < nr && y >= 0) {
            float vR[16], vG[16], vB[16];
            LOADROW(vR, 0, r) LOADROW(vG, 1, r) LOADROW(vB, 2, r)
            u32 bl = nbl[k], bh = nbh[k];
#pragma unroll
            for (int j = 0; j < 14; ++j) {
                u32 bin = ((j < 8) ? (bl >> (4 * j))
                                   : (bh >> (4 * (j - 8)))) & 0xFu;
                float hm = (bin == best) ? 1.0f : 0.0f;
                sr = __builtin_fmaf(hm, vR[j], sr);
                sg = __builtin_fmaf(hm, vG[j], sg);
                sb = __builtin_fmaf(hm, vB[j], sb);
            }
        }
    }
    sr += __shfl_xor(sr, 16);  sr += __shfl_xor(sr, 32);
    sg += __shfl_xor(sg, 16);  sg += __shfl_xor(sg, 32);
    sb += __shfl_xor(sb, 16);  sb += __shfl_xor(sb, 32);

    if (qid == 0) ss[w][cl] = make_float4(sr, sg, sb, 0.f);
    __syncthreads();

    float4 s0 = ss[0][cl], s1 = ss[1][cl];
    float fbc = (float)bc;
    float orv = (s0.x + s1.x) / fbc;
    float ogv = (s0.y + s1.y) / fbc;
    float obv = (s0.z + s1.z) / fbc;

    // ---- write: part p owns row p of the 8x8 block, 2x float4 per channel ----
    size_t base = (size_t)(oy * 8 + p) * Wd + (size_t)(ox * 8);
    float vals[3] = { orv, ogv, obv };
#pragma unroll
    for (int c = 0; c < 3; ++c) {
        float v = vals[c];
        float4 vv = make_float4(v, v, v, v);
        float* o = out + (size_t)c * HW + base;
        ((float4*)o)[0] = vv;
        ((float4*)o)[1] = vv;
    }
#undef LOADROW
}

extern "C" void kernel_launch(void* const* d_in, const int* in_sizes, int n_in,
                              void* d_out, int out_size, void* d_ws, size_t ws_size,
                              hipStream_t stream) {
    const float* rgb = (const float*)d_in[0];
    float* out = (float*)d_out;
    dim3 block(128, 1, 1);                // 2 waves; wave = 16 cells x 4 parts
    dim3 grid(4096, 1, 1);                // 16 strips/cell-row x 256 rows (swizzled)
    hipLaunchKernelGGL(pixel_effect_kernel, grid, block, 0, stream, rgb, out);
}